// Round 16
// baseline (1810.602 us; speedup 1.0000x reference)
//
#include <hip/hip_runtime.h>

#define B_ 512
#define L_ 1000
#define H_ 128
#define G_ 512  // 4*H

typedef _Float16 v8h __attribute__((ext_vector_type(8)));
typedef float v4f __attribute__((ext_vector_type(4)));

__device__ __forceinline__ float sigmoid_f(float x) {
  return __builtin_amdgcn_rcpf(1.0f + __builtin_amdgcn_exp2f(-1.4426950408889634f * x));
}
__device__ __forceinline__ float tanh_f(float x) {
  return 1.0f - 2.0f * __builtin_amdgcn_rcpf(1.0f + __builtin_amdgcn_exp2f(2.8853900817779268f * x));
}
// constant-index extract tree: 3 v_cndmask, no scratch (rule #20 safe)
__device__ __forceinline__ float sel4(v4f v, int j) {
  float lo = (j & 1) ? v[1] : v[0];
  float hi = (j & 1) ? v[3] : v[2];
  return (j & 2) ? hi : lo;
}

// h storage in B-FRAGMENT ORDER: chunk (kt, quad', row) at byte offset
// kt*144 + quad'*32 + row*16 holds h_row[kt*32 + quad'*8 + jj], jj=0..7 (f16).
// C-read (per kt): quad*32 + (m15&1)*16 -> broadcast, zero conflicts
// (verified r10/r12: SQ_LDS_BANK_CONFLICT = 0).
#define FB_KT 144

#define MFMA16(a, b, c) __builtin_amdgcn_mfma_f32_16x16x32_f16((a), (b), (c), 0, 0, 0)

// ROUND-15 (= FUSED-8-PIPE, third submit; 2x audited, infra fails only).
// r12 (1414us) left the machine issue-saturated at 85% (MfmaUtil 45.9 +
// VALUBusy 39.1) with 2 bursts + 2 barriers/step and U-VALU serialized
// after each burst in wave-lockstep. This design: 1-barrier 1-burst
// schedule via software-pipelining U1 one step ahead.
// Segment s (s=0..L-1), entry state: hb1[s&1]=h1(s), hb2[(s+1)&1]=h2(s-1):
//   MFMA: d(s)   = bbb2 + A2i@h1(s) + A2h@h2(s-1)   (32 MFMA/wave, first)
//         a(s+1) = bbb1 + A1@h1(s)                   (16 MFMA/wave)
//   VALU: U2(s) from d -> hb2[s&1]; out(s) shfl+atomic   (overlaps a-burst)
//         U1(s+1) from a + wx*x[s+1] -> hb1[(s+1)&1]     (skip at s=L-1)
//   barrier (ONE per step; 2000 -> 1000 total)
// Parity audit: reads {hb1[s&1], hb2[(s+1)&1]}, writes {hb2[s&1],
// hb1[(s+1)&1]} -> read-parity and write-parity disjoint per buffer; the
// single barrier closes all cross-segment edges. Prologue: h1(0) =
// U1(bbb1, x[0]) (h1(-1)=0, no MFMA needed); hb2 zeroed = h2(-1)=0.
// The 2 waves/SIMD drift inside the long segment -> one wave's U-VALU
// overlaps the other's MFMA (m114 separate pipes).
__global__ __launch_bounds__(512, 2) void lstm_mfma(
    const float* __restrict__ x,
    const float* __restrict__ w_ih1,
    const float* __restrict__ w_hh1,
    const float* __restrict__ b_ih1,
    const float* __restrict__ b_hh1,
    const float* __restrict__ w_ih2,
    const float* __restrict__ w_hh2,
    const float* __restrict__ b_ih2,
    const float* __restrict__ b_hh2,
    const float* __restrict__ w_lin,
    const float* __restrict__ b_lin,
    float* __restrict__ out)
{
  __shared__ __align__(16) float xlds[2][L_];        // block's 2 x-rows
  __shared__ __align__(16) float olds[2 * L_];       // out accum (atomics)
  __shared__ __align__(16) unsigned char hb1[2][4 * FB_KT];  // [parity] h1
  __shared__ __align__(16) unsigned char hb2[2][4 * FB_KT];  // [parity] h2
  __shared__ __align__(16) float bbb1[G_];           // b_ih1+b_hh1 (MFMA C-in)
  __shared__ __align__(16) float bbb2[G_];           // b_ih2+b_hh2

  const int tid  = threadIdx.x;        // 0..511
  const int wv   = tid >> 6;           // 0..7
  const int lane = tid & 63;
  const int quad = lane >> 4;
  const int m15  = lane & 15;
  const int r0   = blockIdx.x * 2;

  // ---- one-time staging / zero-init ----
  for (int i = tid; i < 2 * L_; i += 512) {
    ((float*)xlds)[i] = x[r0 * L_ + i];
    olds[i] = 0.f;
  }
  bbb1[tid] = b_ih1[tid] + b_hh1[tid];   // tid spans exactly G_
  bbb2[tid] = b_ih2[tid] + b_hh2[tid];
  if (tid < 288) {                        // 2*4*FB_KT/4 dwords
    ((unsigned*)hb1)[tid] = 0u;
    ((unsigned*)hb2)[tid] = 0u;           // h2(-1)=0 (both parities)
  }
  const float blv = b_lin[0];

  // ---- per-lane element assignment: column-pair (2k,2k+1) owns j=k ----
  const int jsel = (m15 >> 1) & 3;                 // m15>=8 aliases j=0 (masked)
  const int rsel = m15 & 1;                        // batch row
  const int esel = 16 * wv + 4 * quad + jsel;      // owned h-element
  const float wxi_s = w_ih1[esel];
  const float wxf_s = w_ih1[128 + esel];
  const float wxg_s = w_ih1[256 + esel];
  const float wxo_s = w_ih1[384 + esel];
  const float wl_s  = w_lin[esel];
  // 1-element f16 write offset for (esel, rsel)
  const int hwo1 = (wv >> 1) * FB_KT + (2 * (wv & 1) + (quad >> 1)) * 32
                 + rsel * 16 + (4 * (quad & 1) + jsel) * 2;

  // ---- per-wave fragments: mtiles {wv, 8+wv, 16+wv, 24+wv} (i,f,g,o) ----
  v8h A1f[4][4], A2if[4][4], A2hf[4][4];
#pragma unroll
  for (int m = 0; m < 4; ++m) {
    const int grow = ((wv + 8 * m) * 16 + m15) * H_;
#pragma unroll
    for (int kt = 0; kt < 4; ++kt) {
      const int koff = kt * 32 + quad * 8;
      float4 a, b;
      a = *(const float4*)(w_hh1 + grow + koff);
      b = *(const float4*)(w_hh1 + grow + koff + 4);
      A1f[m][kt] = v8h{(_Float16)a.x, (_Float16)a.y, (_Float16)a.z, (_Float16)a.w,
                       (_Float16)b.x, (_Float16)b.y, (_Float16)b.z, (_Float16)b.w};
      a = *(const float4*)(w_ih2 + grow + koff);
      b = *(const float4*)(w_ih2 + grow + koff + 4);
      A2if[m][kt] = v8h{(_Float16)a.x, (_Float16)a.y, (_Float16)a.z, (_Float16)a.w,
                        (_Float16)b.x, (_Float16)b.y, (_Float16)b.z, (_Float16)b.w};
      a = *(const float4*)(w_hh2 + grow + koff);
      b = *(const float4*)(w_hh2 + grow + koff + 4);
      A2hf[m][kt] = v8h{(_Float16)a.x, (_Float16)a.y, (_Float16)a.z, (_Float16)a.w,
                        (_Float16)b.x, (_Float16)b.y, (_Float16)b.z, (_Float16)b.w};
    }
  }

  float c1 = 0.f, c2 = 0.f;  // in-lane cell state for element (esel, rsel)

  const int cbase = 16 * wv + 4 * quad;            // MFMA acc-init index
  const int roff  = quad * 32 + (m15 & 1) * 16;    // B-frag read offset

  __syncthreads();

  // ---- prologue: h1(0) = U1(bbb1 + wx*x[0]) (A1@h1(-1) = 0) -> hb1[0] ----
  {
    const float xv = xlds[rsel][0];
    float iv = sigmoid_f(bbb1[esel] + wxi_s * xv);
    float fv = sigmoid_f(bbb1[128 + esel] + wxf_s * xv);
    float gv = tanh_f(bbb1[256 + esel] + wxg_s * xv);
    float ov = sigmoid_f(bbb1[384 + esel] + wxo_s * xv);
    c1 = iv * gv;  // f*c(-1) + i*g with c(-1)=0
    float h = ov * tanh_f(c1);
    if (m15 < 8) *(_Float16*)(&hb1[0][0] + hwo1) = (_Float16)h;
  }
  __syncthreads();

  for (int s = 0; s < L_; ++s) {
    // ===== MFMA burst: d(s) [32] then a(s+1) [16] =====
    v4f d0 = *(const v4f*)&bbb2[cbase];
    v4f d1 = *(const v4f*)&bbb2[128 + cbase];
    v4f d2 = *(const v4f*)&bbb2[256 + cbase];
    v4f d3 = *(const v4f*)&bbb2[384 + cbase];
    const unsigned char* p1 = &hb1[s & 1][0];        // h1(s)
    const unsigned char* p2 = &hb2[(s + 1) & 1][0];  // h2(s-1)
    __builtin_amdgcn_s_setprio(1);
#pragma unroll
    for (int kt = 0; kt < 4; ++kt) {
      v8h b1 = *(const v8h*)(p1 + kt * FB_KT + roff);
      v8h b2 = *(const v8h*)(p2 + kt * FB_KT + roff);
      d0 = MFMA16(A2if[0][kt], b1, d0);
      d1 = MFMA16(A2if[1][kt], b1, d1);
      d2 = MFMA16(A2if[2][kt], b1, d2);
      d3 = MFMA16(A2if[3][kt], b1, d3);
      d0 = MFMA16(A2hf[0][kt], b2, d0);
      d1 = MFMA16(A2hf[1][kt], b2, d1);
      d2 = MFMA16(A2hf[2][kt], b2, d2);
      d3 = MFMA16(A2hf[3][kt], b2, d3);
    }
    v4f a0 = *(const v4f*)&bbb1[cbase];
    v4f a1 = *(const v4f*)&bbb1[128 + cbase];
    v4f a2 = *(const v4f*)&bbb1[256 + cbase];
    v4f a3 = *(const v4f*)&bbb1[384 + cbase];
#pragma unroll
    for (int kt = 0; kt < 4; ++kt) {
      v8h b1 = *(const v8h*)(p1 + kt * FB_KT + roff);
      a0 = MFMA16(A1f[0][kt], b1, a0);
      a1 = MFMA16(A1f[1][kt], b1, a1);
      a2 = MFMA16(A1f[2][kt], b1, a2);
      a3 = MFMA16(A1f[3][kt], b1, a3);
    }
    __builtin_amdgcn_s_setprio(0);

    // ===== U2(s): from d -> hb2[s&1]; out(s) (overlaps a-burst in pipe) =====
    {
      float iv = sigmoid_f(sel4(d0, jsel));
      float fv = sigmoid_f(sel4(d1, jsel));
      float gv = tanh_f(sel4(d2, jsel));
      float ov = sigmoid_f(sel4(d3, jsel));
      c2 = fv * c2 + iv * gv;
      float h = ov * tanh_f(c2);
      if (m15 < 8) *(_Float16*)(&hb2[s & 1][0] + hwo1) = (_Float16)h;
      float p = (m15 < 8) ? h * wl_s : 0.f;  // m15>=8 alias j=0: mask out
      p += __shfl_xor(p, 2, 64);
      p += __shfl_xor(p, 4, 64);
      p += __shfl_xor(p, 16, 64);
      p += __shfl_xor(p, 32, 64);
      if (lane < 2) atomicAdd(&olds[lane * L_ + s], p);
    }
    // ===== U1(s+1): from a + wx*x[s+1] -> hb1[(s+1)&1] =====
    if (s + 1 < L_) {
      const float xv = xlds[rsel][s + 1];
      float iv = sigmoid_f(sel4(a0, jsel) + wxi_s * xv);
      float fv = sigmoid_f(sel4(a1, jsel) + wxf_s * xv);
      float gv = tanh_f(sel4(a2, jsel) + wxg_s * xv);
      float ov = sigmoid_f(sel4(a3, jsel) + wxo_s * xv);
      c1 = fv * c1 + iv * gv;
      float h = ov * tanh_f(c1);
      if (m15 < 8) *(_Float16*)(&hb1[(s + 1) & 1][0] + hwo1) = (_Float16)h;
    }
    __syncthreads();
  }

  // ---- one-shot coalesced flush (add output bias once) ----
  for (int i = tid; i < 2 * L_; i += 512) out[r0 * L_ + i] = olds[i] + blv;
}

extern "C" void kernel_launch(void* const* d_in, const int* in_sizes, int n_in,
                              void* d_out, int out_size, void* d_ws, size_t ws_size,
                              hipStream_t stream) {
  const float* x     = (const float*)d_in[0];
  const float* w_ih1 = (const float*)d_in[1];
  const float* w_hh1 = (const float*)d_in[2];
  const float* b_ih1 = (const float*)d_in[3];
  const float* b_hh1 = (const float*)d_in[4];
  const float* w_ih2 = (const float*)d_in[5];
  const float* w_hh2 = (const float*)d_in[6];
  const float* b_ih2 = (const float*)d_in[7];
  const float* b_hh2 = (const float*)d_in[8];
  const float* w_lin = (const float*)d_in[9];
  const float* b_lin = (const float*)d_in[10];

  lstm_mfma<<<B_ / 2, 512, 0, stream>>>(
      x, w_ih1, w_hh1, b_ih1, b_hh1, w_ih2, w_hh2, b_ih2, b_hh2,
      w_lin, b_lin, (float*)d_out);
}

// Round 17
// 1398.056 us; speedup vs baseline: 1.2951x; 1.2951x over previous
//
#include <hip/hip_runtime.h>

#define B_ 512
#define L_ 1000
#define H_ 128
#define G_ 512  // 4*H

typedef _Float16 v8h __attribute__((ext_vector_type(8)));
typedef float v4f __attribute__((ext_vector_type(4)));

__device__ __forceinline__ float sigmoid_f(float x) {
  return __builtin_amdgcn_rcpf(1.0f + __builtin_amdgcn_exp2f(-1.4426950408889634f * x));
}
__device__ __forceinline__ float tanh_f(float x) {
  return 1.0f - 2.0f * __builtin_amdgcn_rcpf(1.0f + __builtin_amdgcn_exp2f(2.8853900817779268f * x));
}
// constant-index extract tree: 3 v_cndmask, no scratch (rule #20 safe)
__device__ __forceinline__ float sel4(v4f v, int j) {
  float lo = (j & 1) ? v[1] : v[0];
  float hi = (j & 1) ? v[3] : v[2];
  return (j & 2) ? hi : lo;
}

// h storage in B-FRAGMENT ORDER: chunk (kt, quad', row) at byte offset
// kt*144 + quad'*32 + row*16 holds h_row[kt*32 + quad'*8 + jj], jj=0..7 (f16).
// C-read (per kt): quad*32 + (m15&1)*16 -> broadcast, zero conflicts
// (verified r10/r12: SQ_LDS_BANK_CONFLICT = 0).
#define FB_KT 144

#define MFMA16(a, b, c) __builtin_amdgcn_mfma_f32_16x16x32_f16((a), (b), (c), 0, 0, 0)

// ROUND-16: FUSED-8-PIPE-v2. r15's pipe ran 1810us (worse than r12's 1414)
// with FETCH 17->51.5MB / WRITE 27.6->95.7MB: the pre-registered spill
// canary. Cause: d0..d3 and a0..a3 co-live (a-burst issued before U2
// consumed d) pushed the live set past 256 regs/wave -> hot-loop scratch.
// Fix: serialize accumulator lifetimes, KEEP the single barrier. Both
// bursts read only barrier-protected state, so segment-internal order is
// free:  d-burst -> U2(s) [d dies] -> a-burst -> U1(s+1) [a dies] -> bar.
// Wave drift still overlaps one wave's U-VALU with the other's MFMA
// (m114); barriers stay halved (1000 vs r12's 2000).
// Segment s invariant (entry): hb1[s&1]=h1(s), hb2[(s+1)&1]=h2(s-1).
//   d(s)   = bbb2 + A2i@h1(s) + A2h@h2(s-1)  (32 MFMA/wave)
//   U2(s): gates=sel4(d) -> c2,h2(s) -> hb2[s&1]; out(s) shfl+atomicAdd
//   a(s+1) = bbb1 + A1@h1(s)                  (16 MFMA/wave)
//   U1(s+1): gates=sel4(a)+wx*x[s+1] -> c1,h1(s+1) -> hb1[(s+1)&1]
// Parity: reads {hb1[s&1], hb2[(s+1)&1]}, writes {hb2[s&1], hb1[(s+1)&1]}
// -> disjoint per buffer; single barrier closes all cross-segment edges.
// Prologue: h1(0)=U1(bbb1,x[0]) (h1(-1)=0); hb2 zeroed = h2(-1)=0.
__global__ __launch_bounds__(512, 2) void lstm_mfma(
    const float* __restrict__ x,
    const float* __restrict__ w_ih1,
    const float* __restrict__ w_hh1,
    const float* __restrict__ b_ih1,
    const float* __restrict__ b_hh1,
    const float* __restrict__ w_ih2,
    const float* __restrict__ w_hh2,
    const float* __restrict__ b_ih2,
    const float* __restrict__ b_hh2,
    const float* __restrict__ w_lin,
    const float* __restrict__ b_lin,
    float* __restrict__ out)
{
  __shared__ __align__(16) float xlds[2][L_];        // block's 2 x-rows
  __shared__ __align__(16) float olds[2 * L_];       // out accum (atomics)
  __shared__ __align__(16) unsigned char hb1[2][4 * FB_KT];  // [parity] h1
  __shared__ __align__(16) unsigned char hb2[2][4 * FB_KT];  // [parity] h2
  __shared__ __align__(16) float bbb1[G_];           // b_ih1+b_hh1 (MFMA C-in)
  __shared__ __align__(16) float bbb2[G_];           // b_ih2+b_hh2

  const int tid  = threadIdx.x;        // 0..511
  const int wv   = tid >> 6;           // 0..7
  const int lane = tid & 63;
  const int quad = lane >> 4;
  const int m15  = lane & 15;
  const int r0   = blockIdx.x * 2;

  // ---- one-time staging / zero-init ----
  for (int i = tid; i < 2 * L_; i += 512) {
    ((float*)xlds)[i] = x[r0 * L_ + i];
    olds[i] = 0.f;
  }
  bbb1[tid] = b_ih1[tid] + b_hh1[tid];   // tid spans exactly G_
  bbb2[tid] = b_ih2[tid] + b_hh2[tid];
  if (tid < 288) {                        // 2*4*FB_KT/4 dwords
    ((unsigned*)hb1)[tid] = 0u;
    ((unsigned*)hb2)[tid] = 0u;           // h2(-1)=0 (both parities)
  }
  const float blv = b_lin[0];

  // ---- per-lane element assignment: column-pair (2k,2k+1) owns j=k ----
  const int jsel = (m15 >> 1) & 3;                 // m15>=8 aliases j=0 (masked)
  const int rsel = m15 & 1;                        // batch row
  const int esel = 16 * wv + 4 * quad + jsel;      // owned h-element
  const float wxi_s = w_ih1[esel];
  const float wxf_s = w_ih1[128 + esel];
  const float wxg_s = w_ih1[256 + esel];
  const float wxo_s = w_ih1[384 + esel];
  const float wl_s  = w_lin[esel];
  // 1-element f16 write offset for (esel, rsel)
  const int hwo1 = (wv >> 1) * FB_KT + (2 * (wv & 1) + (quad >> 1)) * 32
                 + rsel * 16 + (4 * (quad & 1) + jsel) * 2;

  // ---- per-wave fragments: mtiles {wv, 8+wv, 16+wv, 24+wv} (i,f,g,o) ----
  v8h A1f[4][4], A2if[4][4], A2hf[4][4];
#pragma unroll
  for (int m = 0; m < 4; ++m) {
    const int grow = ((wv + 8 * m) * 16 + m15) * H_;
#pragma unroll
    for (int kt = 0; kt < 4; ++kt) {
      const int koff = kt * 32 + quad * 8;
      float4 a, b;
      a = *(const float4*)(w_hh1 + grow + koff);
      b = *(const float4*)(w_hh1 + grow + koff + 4);
      A1f[m][kt] = v8h{(_Float16)a.x, (_Float16)a.y, (_Float16)a.z, (_Float16)a.w,
                       (_Float16)b.x, (_Float16)b.y, (_Float16)b.z, (_Float16)b.w};
      a = *(const float4*)(w_ih2 + grow + koff);
      b = *(const float4*)(w_ih2 + grow + koff + 4);
      A2if[m][kt] = v8h{(_Float16)a.x, (_Float16)a.y, (_Float16)a.z, (_Float16)a.w,
                        (_Float16)b.x, (_Float16)b.y, (_Float16)b.z, (_Float16)b.w};
      a = *(const float4*)(w_hh2 + grow + koff);
      b = *(const float4*)(w_hh2 + grow + koff + 4);
      A2hf[m][kt] = v8h{(_Float16)a.x, (_Float16)a.y, (_Float16)a.z, (_Float16)a.w,
                        (_Float16)b.x, (_Float16)b.y, (_Float16)b.z, (_Float16)b.w};
    }
  }

  float c1 = 0.f, c2 = 0.f;  // in-lane cell state for element (esel, rsel)

  const int cbase = 16 * wv + 4 * quad;            // MFMA acc-init index
  const int roff  = quad * 32 + (m15 & 1) * 16;    // B-frag read offset

  __syncthreads();

  // ---- prologue: h1(0) = U1(bbb1 + wx*x[0]) (A1@h1(-1) = 0) -> hb1[0] ----
  {
    const float xv = xlds[rsel][0];
    float iv = sigmoid_f(bbb1[esel] + wxi_s * xv);
    float fv = sigmoid_f(bbb1[128 + esel] + wxf_s * xv);
    float gv = tanh_f(bbb1[256 + esel] + wxg_s * xv);
    float ov = sigmoid_f(bbb1[384 + esel] + wxo_s * xv);
    c1 = iv * gv;  // f*c(-1) + i*g with c(-1)=0
    float h = ov * tanh_f(c1);
    if (m15 < 8) *(_Float16*)(&hb1[0][0] + hwo1) = (_Float16)h;
  }
  __syncthreads();

  for (int s = 0; s < L_; ++s) {
    const unsigned char* p1 = &hb1[s & 1][0];        // h1(s)
    const unsigned char* p2 = &hb2[(s + 1) & 1][0];  // h2(s-1)

    // ===== d-burst: d(s) = bbb2 + A2i@h1(s) + A2h@h2(s-1)  [32 MFMA] =====
    {
      v4f d0 = *(const v4f*)&bbb2[cbase];
      v4f d1 = *(const v4f*)&bbb2[128 + cbase];
      v4f d2 = *(const v4f*)&bbb2[256 + cbase];
      v4f d3 = *(const v4f*)&bbb2[384 + cbase];
      __builtin_amdgcn_s_setprio(1);
#pragma unroll
      for (int kt = 0; kt < 4; ++kt) {
        v8h b1 = *(const v8h*)(p1 + kt * FB_KT + roff);
        v8h b2 = *(const v8h*)(p2 + kt * FB_KT + roff);
        d0 = MFMA16(A2if[0][kt], b1, d0);
        d1 = MFMA16(A2if[1][kt], b1, d1);
        d2 = MFMA16(A2if[2][kt], b1, d2);
        d3 = MFMA16(A2if[3][kt], b1, d3);
        d0 = MFMA16(A2hf[0][kt], b2, d0);
        d1 = MFMA16(A2hf[1][kt], b2, d1);
        d2 = MFMA16(A2hf[2][kt], b2, d2);
        d3 = MFMA16(A2hf[3][kt], b2, d3);
      }
      __builtin_amdgcn_s_setprio(0);

      // ===== U2(s): from d -> hb2[s&1]; out(s)  [d dies here] =====
      float iv = sigmoid_f(sel4(d0, jsel));
      float fv = sigmoid_f(sel4(d1, jsel));
      float gv = tanh_f(sel4(d2, jsel));
      float ov = sigmoid_f(sel4(d3, jsel));
      c2 = fv * c2 + iv * gv;
      float h = ov * tanh_f(c2);
      if (m15 < 8) *(_Float16*)(&hb2[s & 1][0] + hwo1) = (_Float16)h;
      float p = (m15 < 8) ? h * wl_s : 0.f;  // m15>=8 alias j=0: mask out
      p += __shfl_xor(p, 2, 64);
      p += __shfl_xor(p, 4, 64);
      p += __shfl_xor(p, 16, 64);
      p += __shfl_xor(p, 32, 64);
      if (lane < 2) atomicAdd(&olds[lane * L_ + s], p);
    }

    // ===== a-burst: a(s+1) = bbb1 + A1@h1(s)  [16 MFMA]; U1(s+1) =====
    if (s + 1 < L_) {
      v4f a0 = *(const v4f*)&bbb1[cbase];
      v4f a1 = *(const v4f*)&bbb1[128 + cbase];
      v4f a2 = *(const v4f*)&bbb1[256 + cbase];
      v4f a3 = *(const v4f*)&bbb1[384 + cbase];
      __builtin_amdgcn_s_setprio(1);
#pragma unroll
      for (int kt = 0; kt < 4; ++kt) {
        v8h b1 = *(const v8h*)(p1 + kt * FB_KT + roff);
        a0 = MFMA16(A1f[0][kt], b1, a0);
        a1 = MFMA16(A1f[1][kt], b1, a1);
        a2 = MFMA16(A1f[2][kt], b1, a2);
        a3 = MFMA16(A1f[3][kt], b1, a3);
      }
      __builtin_amdgcn_s_setprio(0);

      const float xv = xlds[rsel][s + 1];
      float iv = sigmoid_f(sel4(a0, jsel) + wxi_s * xv);
      float fv = sigmoid_f(sel4(a1, jsel) + wxf_s * xv);
      float gv = tanh_f(sel4(a2, jsel) + wxg_s * xv);
      float ov = sigmoid_f(sel4(a3, jsel) + wxo_s * xv);
      c1 = fv * c1 + iv * gv;
      float h = ov * tanh_f(c1);
      if (m15 < 8) *(_Float16*)(&hb1[(s + 1) & 1][0] + hwo1) = (_Float16)h;
    }
    __syncthreads();
  }

  // ---- one-shot coalesced flush (add output bias once) ----
  for (int i = tid; i < 2 * L_; i += 512) out[r0 * L_ + i] = olds[i] + blv;
}

extern "C" void kernel_launch(void* const* d_in, const int* in_sizes, int n_in,
                              void* d_out, int out_size, void* d_ws, size_t ws_size,
                              hipStream_t stream) {
  const float* x     = (const float*)d_in[0];
  const float* w_ih1 = (const float*)d_in[1];
  const float* w_hh1 = (const float*)d_in[2];
  const float* b_ih1 = (const float*)d_in[3];
  const float* b_hh1 = (const float*)d_in[4];
  const float* w_ih2 = (const float*)d_in[5];
  const float* w_hh2 = (const float*)d_in[6];
  const float* b_ih2 = (const float*)d_in[7];
  const float* b_hh2 = (const float*)d_in[8];
  const float* w_lin = (const float*)d_in[9];
  const float* b_lin = (const float*)d_in[10];

  lstm_mfma<<<B_ / 2, 512, 0, stream>>>(
      x, w_ih1, w_hh1, b_ih1, b_hh1, w_ih2, w_hh2, b_ih2, b_hh2,
      w_lin, b_lin, (float*)d_out);
}